// Round 2
// baseline (279.202 us; speedup 1.0000x reference)
//
#include <hip/hip_runtime.h>
#include <hip/hip_bf16.h>

#define B_  8
#define Q_  32
#define LE_ 128
#define D_  512
#define P_  32
#define A_  128

__device__ __forceinline__ float fast_tanh(float x) {
    // tanh(x) = 1 - 2/(1+e^{2x}); large |x| saturates correctly (exp->inf or 0)
    float e = __expf(x + x);
    return 1.0f - __fdividef(2.0f, e + 1.0f);
}

// ---------------- K1: ws[b,p,a] = s_j[b,p,:]·Ws_w[a,:] + Ws_b[a] ----------------
__global__ __launch_bounds__(128) void ws_kernel(
    const float* __restrict__ s_j, const float* __restrict__ Ws_w,
    const float* __restrict__ Ws_b, float* __restrict__ ws) {
    __shared__ float s_row[D_];
    int bp = blockIdx.x;
    const float* src = s_j + (size_t)bp * D_;
    for (int i = threadIdx.x; i < D_; i += 128) s_row[i] = src[i];
    __syncthreads();
    int a = threadIdx.x;
    const float4* w4 = (const float4*)(Ws_w + (size_t)a * D_);
    const float4* s4 = (const float4*)s_row;
    float acc = 0.0f;
#pragma unroll 8
    for (int i = 0; i < D_ / 4; ++i) {
        float4 w = w4[i];
        float4 s = s4[i];
        acc += w.x * s.x + w.y * s.y + w.z * s.z + w.w * s.w;
    }
    ws[bp * A_ + a] = acc + Ws_b[a];
}

// ---------------- K2: uh GEMM  (M=32768, N=128, K=512), fp32 -------------------
// uh[m][n] = sum_k X[m][k] * W[n][k]   (both K-contiguous)
#define BM_ 64
#define BK_ 32
#define BMp_ 68
#define BNp_ 132

__global__ __launch_bounds__(256) void uh_kernel(
    const float* __restrict__ X, const float* __restrict__ W,
    float* __restrict__ uh) {
    __shared__ float As[BK_][BMp_];   // [k][m]
    __shared__ float Bs[BK_][BNp_];   // [k][n]
    int mblk = blockIdx.x * BM_;
    int tid = threadIdx.x;
    int tn = tid & 15, tm = tid >> 4;
    int n0 = tn * 8, m0 = tm * 4;

    float acc[4][8];
#pragma unroll
    for (int i = 0; i < 4; ++i)
#pragma unroll
        for (int j = 0; j < 8; ++j) acc[i][j] = 0.0f;

    for (int kt = 0; kt < D_ / BK_; ++kt) {
        int k0 = kt * BK_;
        __syncthreads();
        // stage A: 64 rows x 32 k = 512 float4
#pragma unroll
        for (int i = 0; i < 2; ++i) {
            int f = tid + i * 256;
            int r = f >> 3, c4 = f & 7;
            float4 v = *(const float4*)(X + (size_t)(mblk + r) * D_ + k0 + c4 * 4);
            As[c4 * 4 + 0][r] = v.x;
            As[c4 * 4 + 1][r] = v.y;
            As[c4 * 4 + 2][r] = v.z;
            As[c4 * 4 + 3][r] = v.w;
        }
        // stage B: 128 rows x 32 k = 1024 float4
#pragma unroll
        for (int i = 0; i < 4; ++i) {
            int f = tid + i * 256;
            int n = f >> 3, c4 = f & 7;
            float4 v = *(const float4*)(W + (size_t)n * D_ + k0 + c4 * 4);
            Bs[c4 * 4 + 0][n] = v.x;
            Bs[c4 * 4 + 1][n] = v.y;
            Bs[c4 * 4 + 2][n] = v.z;
            Bs[c4 * 4 + 3][n] = v.w;
        }
        __syncthreads();
#pragma unroll 8
        for (int k = 0; k < BK_; ++k) {
            float4 av = *(const float4*)&As[k][m0];
            float4 b0 = *(const float4*)&Bs[k][n0];
            float4 b1 = *(const float4*)&Bs[k][n0 + 4];
            float ar[4] = {av.x, av.y, av.z, av.w};
            float br[8] = {b0.x, b0.y, b0.z, b0.w, b1.x, b1.y, b1.z, b1.w};
#pragma unroll
            for (int i = 0; i < 4; ++i)
#pragma unroll
                for (int j = 0; j < 8; ++j)
                    acc[i][j] = fmaf(ar[i], br[j], acc[i][j]);
        }
    }
#pragma unroll
    for (int i = 0; i < 4; ++i) {
        float4 lo = make_float4(acc[i][0], acc[i][1], acc[i][2], acc[i][3]);
        float4 hi = make_float4(acc[i][4], acc[i][5], acc[i][6], acc[i][7]);
        float* dst = uh + (size_t)(mblk + m0 + i) * A_ + n0;
        *(float4*)dst = lo;
        *(float4*)(dst + 4) = hi;
    }
}

// -------- K3: e[b,q,p,t] = sum_a v[a]*tanh(uh[bq,t,a] + ws[b,p,a]), masked ------
// grid: (b*Q+q)*4 + tchunk ; block 256
__global__ __launch_bounds__(256) void score_kernel(
    const float* __restrict__ uh, const float* __restrict__ ws,
    const float* __restrict__ v_w, const int* __restrict__ exp_mask,
    float* __restrict__ e) {
    __shared__ float uh_t[32][132];  // [t][a], padded
    __shared__ float ws_t[32][128];  // [p][a]
    __shared__ float v_s[128];
    int blk = blockIdx.x;
    int bq = blk >> 2, tc = blk & 3;
    int b = bq >> 5;  // Q=32
    int t0 = tc * 32;
    int tid = threadIdx.x;

#pragma unroll
    for (int i = 0; i < 4; ++i) {
        int f = tid + i * 256;          // 0..1023
        int t = f >> 5, a4 = f & 31;
        float4 v = *(const float4*)(uh + (size_t)(bq * LE_ + t0 + t) * A_ + a4 * 4);
        *(float4*)&uh_t[t][a4 * 4] = v;
    }
#pragma unroll
    for (int i = 0; i < 4; ++i) {
        int f = tid + i * 256;
        int p = f >> 5, a4 = f & 31;
        *(float4*)&ws_t[p][a4 * 4] =
            *(const float4*)(ws + (size_t)(b * P_ + p) * A_ + a4 * 4);
    }
    if (tid < 32) *(float4*)&v_s[tid * 4] = *(const float4*)(v_w + tid * 4);
    __syncthreads();

    int t = tid & 31, pb = tid >> 5;  // pb 0..7
    int mask = exp_mask[bq * LE_ + t0 + t];
    float acc[4] = {0.f, 0.f, 0.f, 0.f};
    for (int a4 = 0; a4 < 32; ++a4) {
        float4 u = *(const float4*)&uh_t[t][a4 * 4];
        float4 vv = *(const float4*)&v_s[a4 * 4];
#pragma unroll
        for (int i = 0; i < 4; ++i) {
            float4 w = *(const float4*)&ws_t[pb + i * 8][a4 * 4];
            acc[i] += vv.x * fast_tanh(u.x + w.x)
                    + vv.y * fast_tanh(u.y + w.y)
                    + vv.z * fast_tanh(u.z + w.z)
                    + vv.w * fast_tanh(u.w + w.w);
        }
    }
#pragma unroll
    for (int i = 0; i < 4; ++i) {
        int p = pb + i * 8;
        e[(size_t)(bq * P_ + p) * LE_ + t0 + t] = mask ? acc[i] : -1e9f;
    }
}

// -------- K4: per (b,p): m = max over (q,t), s = sum exp(e-m); stats = {m, 1/s} --
__global__ __launch_bounds__(256) void softmax_stats_kernel(
    const float* __restrict__ e, float* __restrict__ stats) {
    __shared__ float red[16];
    int bp = blockIdx.x;
    int b = bp >> 5, p = bp & 31;  // P=32
    int tid = threadIdx.x;
    float vals[16];
#pragma unroll
    for (int i = 0; i < 16; ++i) {
        int idx = tid + i * 256;  // 0..4095
        int q = idx >> 7, t = idx & 127;
        vals[i] = e[(size_t)((b * Q_ + q) * P_ + p) * LE_ + t];
    }
    float m = -1e30f;
#pragma unroll
    for (int i = 0; i < 16; ++i) m = fmaxf(m, vals[i]);
    for (int off = 32; off; off >>= 1) m = fmaxf(m, __shfl_down(m, off));
    int wid = tid >> 6;
    if ((tid & 63) == 0) red[wid] = m;
    __syncthreads();
    if (tid == 0)
        red[8] = fmaxf(fmaxf(red[0], red[1]), fmaxf(red[2], red[3]));
    __syncthreads();
    m = red[8];
    float s = 0.0f;
#pragma unroll
    for (int i = 0; i < 16; ++i) s += __expf(vals[i] - m);
    for (int off = 32; off; off >>= 1) s += __shfl_down(s, off);
    __syncthreads();
    if ((tid & 63) == 0) red[wid] = s;
    __syncthreads();
    if (tid == 0) {
        float ss = red[0] + red[1] + red[2] + red[3];
        stats[bp * 2 + 0] = m;
        stats[bp * 2 + 1] = 1.0f / ss;
    }
}

// -------- K5: out[b,q,p,d] = req_mask[b,p] * sum_t a[b,q,p,t]*T[b,q,t,d] -------
// grid: (b*Q+q)*2 + dhalf ; block 256, each thread one d column, 32 p accumulators
__global__ __launch_bounds__(256) void out_kernel(
    const float* __restrict__ e, const float* __restrict__ stats,
    const float* __restrict__ exp_tokens, const int* __restrict__ req_mask,
    float* __restrict__ out) {
    __shared__ float w_s[LE_ * P_];  // [t][p]
    int bq = blockIdx.x >> 1, half = blockIdx.x & 1;
    int b = bq >> 5;  // Q=32
    int tid = threadIdx.x;

#pragma unroll
    for (int i = 0; i < 16; ++i) {
        int idx = tid + i * 256;  // 0..4095
        int p = idx >> 7, t = idx & 127;
        int bp = b * P_ + p;
        float m = stats[bp * 2 + 0];
        float rm = req_mask[bp] ? stats[bp * 2 + 1] : 0.0f;
        float ev = e[(size_t)(bq * P_ + p) * LE_ + t];
        w_s[t * P_ + p] = __expf(ev - m) * rm;
    }
    __syncthreads();

    int d = half * 256 + tid;
    const float* T = exp_tokens + (size_t)bq * LE_ * D_;
    float acc[32];
#pragma unroll
    for (int p = 0; p < 32; ++p) acc[p] = 0.0f;

#pragma unroll 4
    for (int t = 0; t < LE_; ++t) {
        float tv = T[(size_t)t * D_ + d];
        const float4* wp = (const float4*)&w_s[t * P_];
#pragma unroll
        for (int j = 0; j < 8; ++j) {
            float4 w = wp[j];
            acc[j * 4 + 0] = fmaf(w.x, tv, acc[j * 4 + 0]);
            acc[j * 4 + 1] = fmaf(w.y, tv, acc[j * 4 + 1]);
            acc[j * 4 + 2] = fmaf(w.z, tv, acc[j * 4 + 2]);
            acc[j * 4 + 3] = fmaf(w.w, tv, acc[j * 4 + 3]);
        }
    }
    float* obase = out + (size_t)(bq * P_) * D_ + d;
#pragma unroll
    for (int p = 0; p < 32; ++p)
        obase[(size_t)p * D_] = acc[p];
}

extern "C" void kernel_launch(void* const* d_in, const int* in_sizes, int n_in,
                              void* d_out, int out_size, void* d_ws, size_t ws_size,
                              hipStream_t stream) {
    const float* exp_tokens = (const float*)d_in[0];
    const int*   exp_mask   = (const int*)d_in[1];
    const float* s_j        = (const float*)d_in[2];
    const int*   req_mask   = (const int*)d_in[3];
    const float* Ws_w       = (const float*)d_in[4];
    const float* Ws_b       = (const float*)d_in[5];
    const float* U_w        = (const float*)d_in[6];
    const float* v_w        = (const float*)d_in[7];
    float* out = (float*)d_out;

    float* ws_buf = (float*)d_ws;                         // B*P*A      = 32768
    float* uh     = ws_buf + B_ * P_ * A_;                // B*Q*LE*A   = 4194304
    float* e      = uh + (size_t)B_ * Q_ * LE_ * A_;      // B*Q*P*LE   = 1048576
    float* stats  = e + (size_t)B_ * Q_ * P_ * LE_;       // 2*B*P      = 512

    ws_kernel<<<dim3(B_ * P_), dim3(128), 0, stream>>>(s_j, Ws_w, Ws_b, ws_buf);
    uh_kernel<<<dim3(B_ * Q_ * LE_ / BM_), dim3(256), 0, stream>>>(exp_tokens, U_w, uh);
    score_kernel<<<dim3(B_ * Q_ * 4), dim3(256), 0, stream>>>(uh, ws_buf, v_w, exp_mask, e);
    softmax_stats_kernel<<<dim3(B_ * P_), dim3(256), 0, stream>>>(e, stats);
    out_kernel<<<dim3(B_ * Q_ * 2), dim3(256), 0, stream>>>(e, stats, exp_tokens, req_mask, out);
}

// Round 3
// 239.691 us; speedup vs baseline: 1.1648x; 1.1648x over previous
//
#include <hip/hip_runtime.h>
#include <hip/hip_bf16.h>

#define B_  8
#define Q_  32
#define LE_ 128
#define D_  512
#define P_  32
#define A_  128

typedef __attribute__((ext_vector_type(8))) short short8_t;   // 8 bf16 (4 VGPRs)
typedef __attribute__((ext_vector_type(4))) float floatx4_t;  // 4 fp32 acc

__device__ __forceinline__ float fast_tanh(float x) {
    float e = __expf(x + x);
    return 1.0f - __fdividef(2.0f, e + 1.0f);
}

// fp32 -> bf16 round-to-nearest-even, raw bits
__device__ __forceinline__ short f2bf(float x) {
    unsigned u = __float_as_uint(x);
    unsigned r = (u + 0x7fffu + ((u >> 16) & 1u)) >> 16;
    return (short)r;
}

// ---------------- K1: ws[b,p,a] = s_j[b,p,:]·Ws_w[a,:] + Ws_b[a] ----------------
__global__ __launch_bounds__(128) void ws_kernel(
    const float* __restrict__ s_j, const float* __restrict__ Ws_w,
    const float* __restrict__ Ws_b, float* __restrict__ ws) {
    __shared__ float s_row[D_];
    int bp = blockIdx.x;
    const float* src = s_j + (size_t)bp * D_;
    for (int i = threadIdx.x; i < D_; i += 128) s_row[i] = src[i];
    __syncthreads();
    int a = threadIdx.x;
    const float4* w4 = (const float4*)(Ws_w + (size_t)a * D_);
    const float4* s4 = (const float4*)s_row;
    float acc = 0.0f;
#pragma unroll 8
    for (int i = 0; i < D_ / 4; ++i) {
        float4 w = w4[i];
        float4 s = s4[i];
        acc += w.x * s.x + w.y * s.y + w.z * s.z + w.w * s.w;
    }
    ws[bp * A_ + a] = acc + Ws_b[a];
}

// ---------------- K2: uh GEMM via bf16 MFMA --------------------------------------
// uh[m][n] = sum_k X[m][k]*W[n][k];  M=32768, N=128, K=512 (NT, both K-contiguous)
// Block: 64M x 128N tile, BK=64. 256 thr = 4 waves, wave tile 32M x 64N.
#define TM_ 64
#define TBK_ 64
#define LDSP_ 72   // padded LDS row (bf16 elems) = 144 B

__global__ __launch_bounds__(256, 2) void uh_mfma_kernel(
    const float* __restrict__ X, const float* __restrict__ W,
    float* __restrict__ uh) {
    __shared__ short As[TM_ * LDSP_];    // [m][k] bf16
    __shared__ short Bs[A_ * LDSP_];     // [n][k] bf16
    int mblk = blockIdx.x * TM_;
    int tid = threadIdx.x;
    int wave = tid >> 6, lane = tid & 63;
    int qd = lane >> 4, lr = lane & 15;
    int mh = wave >> 1, nh = wave & 1;   // wave tile: M 32 x N 64

    floatx4_t acc[2][4];
#pragma unroll
    for (int i = 0; i < 2; ++i)
#pragma unroll
        for (int j = 0; j < 4; ++j) acc[i][j] = (floatx4_t){0.f, 0.f, 0.f, 0.f};

    int ra = tid >> 2, qa = tid & 3;     // A staging: row, 16-col quarter
    int rb = tid >> 1, hb = tid & 1;     // B staging: row, 32-col half

    for (int kt = 0; kt < D_ / TBK_; ++kt) {
        int k0 = kt * TBK_;
        __syncthreads();
        {   // stage A: 64 rows x 64 k fp32 -> bf16
            const float4* src = (const float4*)(X + (size_t)(mblk + ra) * D_ + k0 + qa * 16);
            short* dst = As + ra * LDSP_ + qa * 16;
#pragma unroll
            for (int j = 0; j < 2; ++j) {
                float4 v0 = src[j * 2 + 0];
                float4 v1 = src[j * 2 + 1];
                short8_t s;
                s[0] = f2bf(v0.x); s[1] = f2bf(v0.y); s[2] = f2bf(v0.z); s[3] = f2bf(v0.w);
                s[4] = f2bf(v1.x); s[5] = f2bf(v1.y); s[6] = f2bf(v1.z); s[7] = f2bf(v1.w);
                *(short8_t*)(dst + j * 8) = s;
            }
        }
        {   // stage B: 128 rows x 64 k fp32 -> bf16
            const float4* src = (const float4*)(W + (size_t)rb * D_ + k0 + hb * 32);
            short* dst = Bs + rb * LDSP_ + hb * 32;
#pragma unroll
            for (int j = 0; j < 4; ++j) {
                float4 v0 = src[j * 2 + 0];
                float4 v1 = src[j * 2 + 1];
                short8_t s;
                s[0] = f2bf(v0.x); s[1] = f2bf(v0.y); s[2] = f2bf(v0.z); s[3] = f2bf(v0.w);
                s[4] = f2bf(v1.x); s[5] = f2bf(v1.y); s[6] = f2bf(v1.z); s[7] = f2bf(v1.w);
                *(short8_t*)(dst + j * 8) = s;
            }
        }
        __syncthreads();
#pragma unroll
        for (int ks = 0; ks < 2; ++ks) {
            short8_t af[2], bf[4];
#pragma unroll
            for (int i = 0; i < 2; ++i)
                af[i] = *(const short8_t*)(As + (mh * 32 + i * 16 + lr) * LDSP_ + ks * 32 + qd * 8);
#pragma unroll
            for (int j = 0; j < 4; ++j)
                bf[j] = *(const short8_t*)(Bs + (nh * 64 + j * 16 + lr) * LDSP_ + ks * 32 + qd * 8);
#pragma unroll
            for (int i = 0; i < 2; ++i)
#pragma unroll
                for (int j = 0; j < 4; ++j)
                    acc[i][j] = __builtin_amdgcn_mfma_f32_16x16x32_bf16(af[i], bf[j], acc[i][j], 0, 0, 0);
        }
    }
    // C/D: col = lane&15 (n), row = qd*4+reg (m)
#pragma unroll
    for (int i = 0; i < 2; ++i) {
#pragma unroll
        for (int j = 0; j < 4; ++j) {
            int mg = mblk + mh * 32 + i * 16 + qd * 4;
            int ng = nh * 64 + j * 16 + lr;
            float* dst = uh + (size_t)mg * A_ + ng;
#pragma unroll
            for (int r = 0; r < 4; ++r)
                dst[(size_t)r * A_] = acc[i][j][r];
        }
    }
}

// -------- K3: e[b,q,p,t] = sum_a v[a]*tanh(uh[bq,t,a] + ws[b,p,a]), masked ------
__global__ __launch_bounds__(256) void score_kernel(
    const float* __restrict__ uh, const float* __restrict__ ws,
    const float* __restrict__ v_w, const int* __restrict__ exp_mask,
    float* __restrict__ e) {
    __shared__ float uh_t[32][132];  // [t][a], padded
    __shared__ float ws_t[32][128];  // [p][a]
    __shared__ float v_s[128];
    int blk = blockIdx.x;
    int bq = blk >> 2, tc = blk & 3;
    int b = bq >> 5;  // Q=32
    int t0 = tc * 32;
    int tid = threadIdx.x;

#pragma unroll
    for (int i = 0; i < 4; ++i) {
        int f = tid + i * 256;          // 0..1023
        int t = f >> 5, a4 = f & 31;
        float4 v = *(const float4*)(uh + (size_t)(bq * LE_ + t0 + t) * A_ + a4 * 4);
        *(float4*)&uh_t[t][a4 * 4] = v;
    }
#pragma unroll
    for (int i = 0; i < 4; ++i) {
        int f = tid + i * 256;
        int p = f >> 5, a4 = f & 31;
        *(float4*)&ws_t[p][a4 * 4] =
            *(const float4*)(ws + (size_t)(b * P_ + p) * A_ + a4 * 4);
    }
    if (tid < 32) *(float4*)&v_s[tid * 4] = *(const float4*)(v_w + tid * 4);
    __syncthreads();

    int t = tid & 31, pb = tid >> 5;  // pb 0..7
    int mask = exp_mask[bq * LE_ + t0 + t];
    float acc[4] = {0.f, 0.f, 0.f, 0.f};
    for (int a4 = 0; a4 < 32; ++a4) {
        float4 u = *(const float4*)&uh_t[t][a4 * 4];
        float4 vv = *(const float4*)&v_s[a4 * 4];
#pragma unroll
        for (int i = 0; i < 4; ++i) {
            float4 w = *(const float4*)&ws_t[pb + i * 8][a4 * 4];
            acc[i] += vv.x * fast_tanh(u.x + w.x)
                    + vv.y * fast_tanh(u.y + w.y)
                    + vv.z * fast_tanh(u.z + w.z)
                    + vv.w * fast_tanh(u.w + w.w);
        }
    }
#pragma unroll
    for (int i = 0; i < 4; ++i) {
        int p = pb + i * 8;
        e[(size_t)(bq * P_ + p) * LE_ + t0 + t] = mask ? acc[i] : -1e9f;
    }
}

// -------- K4: per (b,p): m = max over (q,t), s = sum exp(e-m); stats = {m, 1/s} --
__global__ __launch_bounds__(256) void softmax_stats_kernel(
    const float* __restrict__ e, float* __restrict__ stats) {
    __shared__ float red[16];
    int bp = blockIdx.x;
    int b = bp >> 5, p = bp & 31;  // P=32
    int tid = threadIdx.x;
    float vals[16];
#pragma unroll
    for (int i = 0; i < 16; ++i) {
        int idx = tid + i * 256;  // 0..4095
        int q = idx >> 7, t = idx & 127;
        vals[i] = e[(size_t)((b * Q_ + q) * P_ + p) * LE_ + t];
    }
    float m = -1e30f;
#pragma unroll
    for (int i = 0; i < 16; ++i) m = fmaxf(m, vals[i]);
    for (int off = 32; off; off >>= 1) m = fmaxf(m, __shfl_down(m, off));
    int wid = tid >> 6;
    if ((tid & 63) == 0) red[wid] = m;
    __syncthreads();
    if (tid == 0)
        red[8] = fmaxf(fmaxf(red[0], red[1]), fmaxf(red[2], red[3]));
    __syncthreads();
    m = red[8];
    float s = 0.0f;
#pragma unroll
    for (int i = 0; i < 16; ++i) s += __expf(vals[i] - m);
    for (int off = 32; off; off >>= 1) s += __shfl_down(s, off);
    __syncthreads();
    if ((tid & 63) == 0) red[wid] = s;
    __syncthreads();
    if (tid == 0) {
        float ss = red[0] + red[1] + red[2] + red[3];
        stats[bp * 2 + 0] = m;
        stats[bp * 2 + 1] = 1.0f / ss;
    }
}

// -------- K5: out[b,q,p,d] = req_mask[b,p] * sum_t a[b,q,p,t]*T[b,q,t,d] -------
__global__ __launch_bounds__(256) void out_kernel(
    const float* __restrict__ e, const float* __restrict__ stats,
    const float* __restrict__ exp_tokens, const int* __restrict__ req_mask,
    float* __restrict__ out) {
    __shared__ float w_s[LE_ * P_];  // [t][p]
    int bq = blockIdx.x >> 1, half = blockIdx.x & 1;
    int b = bq >> 5;  // Q=32
    int tid = threadIdx.x;

#pragma unroll
    for (int i = 0; i < 16; ++i) {
        int idx = tid + i * 256;  // 0..4095
        int p = idx >> 7, t = idx & 127;
        int bp = b * P_ + p;
        float m = stats[bp * 2 + 0];
        float rm = req_mask[bp] ? stats[bp * 2 + 1] : 0.0f;
        float ev = e[(size_t)(bq * P_ + p) * LE_ + t];
        w_s[t * P_ + p] = __expf(ev - m) * rm;
    }
    __syncthreads();

    int d = half * 256 + tid;
    const float* T = exp_tokens + (size_t)bq * LE_ * D_;
    float acc[32];
#pragma unroll
    for (int p = 0; p < 32; ++p) acc[p] = 0.0f;

#pragma unroll 4
    for (int t = 0; t < LE_; ++t) {
        float tv = T[(size_t)t * D_ + d];
        const float4* wp = (const float4*)&w_s[t * P_];
#pragma unroll
        for (int j = 0; j < 8; ++j) {
            float4 w = wp[j];
            acc[j * 4 + 0] = fmaf(w.x, tv, acc[j * 4 + 0]);
            acc[j * 4 + 1] = fmaf(w.y, tv, acc[j * 4 + 1]);
            acc[j * 4 + 2] = fmaf(w.z, tv, acc[j * 4 + 2]);
            acc[j * 4 + 3] = fmaf(w.w, tv, acc[j * 4 + 3]);
        }
    }
    float* obase = out + (size_t)(bq * P_) * D_ + d;
#pragma unroll
    for (int p = 0; p < 32; ++p)
        obase[(size_t)p * D_] = acc[p];
}

extern "C" void kernel_launch(void* const* d_in, const int* in_sizes, int n_in,
                              void* d_out, int out_size, void* d_ws, size_t ws_size,
                              hipStream_t stream) {
    const float* exp_tokens = (const float*)d_in[0];
    const int*   exp_mask   = (const int*)d_in[1];
    const float* s_j        = (const float*)d_in[2];
    const int*   req_mask   = (const int*)d_in[3];
    const float* Ws_w       = (const float*)d_in[4];
    const float* Ws_b       = (const float*)d_in[5];
    const float* U_w        = (const float*)d_in[6];
    const float* v_w        = (const float*)d_in[7];
    float* out = (float*)d_out;

    float* ws_buf = (float*)d_ws;                         // B*P*A      = 32768
    float* uh     = ws_buf + B_ * P_ * A_;                // B*Q*LE*A   = 4194304
    float* e      = uh + (size_t)B_ * Q_ * LE_ * A_;      // B*Q*P*LE   = 1048576
    float* stats  = e + (size_t)B_ * Q_ * P_ * LE_;       // 2*B*P      = 512

    ws_kernel<<<dim3(B_ * P_), dim3(128), 0, stream>>>(s_j, Ws_w, Ws_b, ws_buf);
    uh_mfma_kernel<<<dim3(B_ * Q_ * LE_ / TM_), dim3(256), 0, stream>>>(exp_tokens, U_w, uh);
    score_kernel<<<dim3(B_ * Q_ * 4), dim3(256), 0, stream>>>(uh, ws_buf, v_w, exp_mask, e);
    softmax_stats_kernel<<<dim3(B_ * P_), dim3(256), 0, stream>>>(e, stats);
    out_kernel<<<dim3(B_ * Q_ * 2), dim3(256), 0, stream>>>(e, stats, exp_tokens, req_mask, out);
}

// Round 4
// 194.720 us; speedup vs baseline: 1.4339x; 1.2309x over previous
//
#include <hip/hip_runtime.h>
#include <hip/hip_bf16.h>

#define B_  8
#define Q_  32
#define LE_ 128
#define D_  512
#define P_  32
#define A_  128

typedef __attribute__((ext_vector_type(8))) short short8_t;   // 8 bf16 (4 VGPRs)
typedef __attribute__((ext_vector_type(4))) float floatx4_t;  // 4 fp32 acc

// fp32 -> bf16 round-to-nearest-even, raw bits
__device__ __forceinline__ short f2bf(float x) {
    unsigned u = __float_as_uint(x);
    unsigned r = (u + 0x7fffu + ((u >> 16) & 1u)) >> 16;
    return (short)r;
}

// ---------------- K1: EW[b,p,a] = exp(2*(s_j[b,p,:]·Ws_w[a,:] + Ws_b[a])) -------
__global__ __launch_bounds__(128) void ws_kernel(
    const float* __restrict__ s_j, const float* __restrict__ Ws_w,
    const float* __restrict__ Ws_b, float* __restrict__ ws) {
    __shared__ float s_row[D_];
    int bp = blockIdx.x;
    const float* src = s_j + (size_t)bp * D_;
    for (int i = threadIdx.x; i < D_; i += 128) s_row[i] = src[i];
    __syncthreads();
    int a = threadIdx.x;
    const float4* w4 = (const float4*)(Ws_w + (size_t)a * D_);
    const float4* s4 = (const float4*)s_row;
    float acc = 0.0f;
#pragma unroll 8
    for (int i = 0; i < D_ / 4; ++i) {
        float4 w = w4[i];
        float4 s = s4[i];
        acc += w.x * s.x + w.y * s.y + w.z * s.z + w.w * s.w;
    }
    ws[bp * A_ + a] = __expf(2.0f * (acc + Ws_b[a]));
}

// ---------------- K2: EU = exp(2*uh), uh via bf16 MFMA ---------------------------
// uh[m][n] = sum_k X[m][k]*W[n][k];  M=32768, N=128, K=512 (NT, both K-contiguous)
#define TM_ 64
#define TBK_ 64
#define LDSP_ 72   // padded LDS row (bf16 elems) = 144 B

__global__ __launch_bounds__(256, 2) void uh_mfma_kernel(
    const float* __restrict__ X, const float* __restrict__ W,
    float* __restrict__ uh) {
    __shared__ short As[TM_ * LDSP_];    // [m][k] bf16
    __shared__ short Bs[A_ * LDSP_];     // [n][k] bf16
    int mblk = blockIdx.x * TM_;
    int tid = threadIdx.x;
    int wave = tid >> 6, lane = tid & 63;
    int qd = lane >> 4, lr = lane & 15;
    int mh = wave >> 1, nh = wave & 1;   // wave tile: M 32 x N 64

    floatx4_t acc[2][4];
#pragma unroll
    for (int i = 0; i < 2; ++i)
#pragma unroll
        for (int j = 0; j < 4; ++j) acc[i][j] = (floatx4_t){0.f, 0.f, 0.f, 0.f};

    int ra = tid >> 2, qa = tid & 3;     // A staging: row, 16-col quarter
    int rb = tid >> 1, hb = tid & 1;     // B staging: row, 32-col half

    for (int kt = 0; kt < D_ / TBK_; ++kt) {
        int k0 = kt * TBK_;
        __syncthreads();
        {   // stage A: 64 rows x 64 k fp32 -> bf16
            const float4* src = (const float4*)(X + (size_t)(mblk + ra) * D_ + k0 + qa * 16);
            short* dst = As + ra * LDSP_ + qa * 16;
#pragma unroll
            for (int j = 0; j < 2; ++j) {
                float4 v0 = src[j * 2 + 0];
                float4 v1 = src[j * 2 + 1];
                short8_t s;
                s[0] = f2bf(v0.x); s[1] = f2bf(v0.y); s[2] = f2bf(v0.z); s[3] = f2bf(v0.w);
                s[4] = f2bf(v1.x); s[5] = f2bf(v1.y); s[6] = f2bf(v1.z); s[7] = f2bf(v1.w);
                *(short8_t*)(dst + j * 8) = s;
            }
        }
        {   // stage B: 128 rows x 64 k fp32 -> bf16
            const float4* src = (const float4*)(W + (size_t)rb * D_ + k0 + hb * 32);
            short* dst = Bs + rb * LDSP_ + hb * 32;
#pragma unroll
            for (int j = 0; j < 4; ++j) {
                float4 v0 = src[j * 2 + 0];
                float4 v1 = src[j * 2 + 1];
                short8_t s;
                s[0] = f2bf(v0.x); s[1] = f2bf(v0.y); s[2] = f2bf(v0.z); s[3] = f2bf(v0.w);
                s[4] = f2bf(v1.x); s[5] = f2bf(v1.y); s[6] = f2bf(v1.z); s[7] = f2bf(v1.w);
                *(short8_t*)(dst + j * 8) = s;
            }
        }
        __syncthreads();
#pragma unroll
        for (int ks = 0; ks < 2; ++ks) {
            short8_t af[2], bf[4];
#pragma unroll
            for (int i = 0; i < 2; ++i)
                af[i] = *(const short8_t*)(As + (mh * 32 + i * 16 + lr) * LDSP_ + ks * 32 + qd * 8);
#pragma unroll
            for (int j = 0; j < 4; ++j)
                bf[j] = *(const short8_t*)(Bs + (nh * 64 + j * 16 + lr) * LDSP_ + ks * 32 + qd * 8);
#pragma unroll
            for (int i = 0; i < 2; ++i)
#pragma unroll
                for (int j = 0; j < 4; ++j)
                    acc[i][j] = __builtin_amdgcn_mfma_f32_16x16x32_bf16(af[i], bf[j], acc[i][j], 0, 0, 0);
        }
    }
    // C/D: col = lane&15 (n), row = qd*4+reg (m); store EU = exp(2*uh)
#pragma unroll
    for (int i = 0; i < 2; ++i) {
#pragma unroll
        for (int j = 0; j < 4; ++j) {
            int mg = mblk + mh * 32 + i * 16 + qd * 4;
            int ng = nh * 64 + j * 16 + lr;
            float* dst = uh + (size_t)mg * A_ + ng;
#pragma unroll
            for (int r = 0; r < 4; ++r)
                dst[(size_t)r * A_] = __expf(2.0f * acc[i][j][r]);
        }
    }
}

// -------- K3: e[b,q,p,t] = sumv - sum_a 2*v[a]/(1 + EU[bq,t,a]*EW[b,p,a]) -------
// grid: (b*Q+q)*4 + tchunk ; block 256
__global__ __launch_bounds__(256) void score_kernel(
    const float* __restrict__ EU, const float* __restrict__ EW,
    const float* __restrict__ v_w, const int* __restrict__ exp_mask,
    float* __restrict__ e) {
    __shared__ float eu_t[32][132];  // [t][a], padded
    __shared__ float ew_t[32][128];  // [p][a]
    __shared__ float n2v[128];       // -2*v[a]
    int blk = blockIdx.x;
    int bq = blk >> 2, tc = blk & 3;
    int b = bq >> 5;  // Q=32
    int t0 = tc * 32;
    int tid = threadIdx.x;

#pragma unroll
    for (int i = 0; i < 4; ++i) {
        int f = tid + i * 256;          // 0..1023
        int t = f >> 5, a4 = f & 31;
        float4 v = *(const float4*)(EU + (size_t)(bq * LE_ + t0 + t) * A_ + a4 * 4);
        *(float4*)&eu_t[t][a4 * 4] = v;
    }
#pragma unroll
    for (int i = 0; i < 4; ++i) {
        int f = tid + i * 256;
        int p = f >> 5, a4 = f & 31;
        *(float4*)&ew_t[p][a4 * 4] =
            *(const float4*)(EW + (size_t)(b * P_ + p) * A_ + a4 * 4);
    }
    if (tid < 32) {
        float4 v = *(const float4*)(v_w + tid * 4);
        v.x *= -2.0f; v.y *= -2.0f; v.z *= -2.0f; v.w *= -2.0f;
        *(float4*)&n2v[tid * 4] = v;
    }
    __syncthreads();

    // sumv = sum_a v[a]  (from n2v, once per thread)
    float sumv = 0.0f;
#pragma unroll
    for (int i = 0; i < 32; ++i) {
        float4 nv = *(const float4*)&n2v[i * 4];
        sumv += nv.x + nv.y + nv.z + nv.w;
    }
    sumv *= -0.5f;

    int t = tid & 31, pb = tid >> 5;  // pb 0..7
    int mask = exp_mask[bq * LE_ + t0 + t];
    float acc[4] = {0.f, 0.f, 0.f, 0.f};
    for (int a4 = 0; a4 < 32; ++a4) {
        float4 u = *(const float4*)&eu_t[t][a4 * 4];
        float4 vv = *(const float4*)&n2v[a4 * 4];
#pragma unroll
        for (int i = 0; i < 4; ++i) {
            float4 w = *(const float4*)&ew_t[pb + i * 8][a4 * 4];
            acc[i] = fmaf(vv.x, __builtin_amdgcn_rcpf(1.0f + u.x * w.x), acc[i]);
            acc[i] = fmaf(vv.y, __builtin_amdgcn_rcpf(1.0f + u.y * w.y), acc[i]);
            acc[i] = fmaf(vv.z, __builtin_amdgcn_rcpf(1.0f + u.z * w.z), acc[i]);
            acc[i] = fmaf(vv.w, __builtin_amdgcn_rcpf(1.0f + u.w * w.w), acc[i]);
        }
    }
#pragma unroll
    for (int i = 0; i < 4; ++i) {
        int p = pb + i * 8;
        e[(size_t)(bq * P_ + p) * LE_ + t0 + t] = mask ? (sumv + acc[i]) : -1e9f;
    }
}

// -------- K4: per (b,p): m = max over (q,t), s = sum exp(e-m); stats = {m, 1/s} --
__global__ __launch_bounds__(256) void softmax_stats_kernel(
    const float* __restrict__ e, float* __restrict__ stats) {
    __shared__ float red[16];
    int bp = blockIdx.x;
    int b = bp >> 5, p = bp & 31;  // P=32
    int tid = threadIdx.x;
    float vals[16];
#pragma unroll
    for (int i = 0; i < 16; ++i) {
        int idx = tid + i * 256;  // 0..4095
        int q = idx >> 7, t = idx & 127;
        vals[i] = e[(size_t)((b * Q_ + q) * P_ + p) * LE_ + t];
    }
    float m = -1e30f;
#pragma unroll
    for (int i = 0; i < 16; ++i) m = fmaxf(m, vals[i]);
    for (int off = 32; off; off >>= 1) m = fmaxf(m, __shfl_down(m, off));
    int wid = tid >> 6;
    if ((tid & 63) == 0) red[wid] = m;
    __syncthreads();
    if (tid == 0)
        red[8] = fmaxf(fmaxf(red[0], red[1]), fmaxf(red[2], red[3]));
    __syncthreads();
    m = red[8];
    float s = 0.0f;
#pragma unroll
    for (int i = 0; i < 16; ++i) s += __expf(vals[i] - m);
    for (int off = 32; off; off >>= 1) s += __shfl_down(s, off);
    __syncthreads();
    if ((tid & 63) == 0) red[wid] = s;
    __syncthreads();
    if (tid == 0) {
        float ss = red[0] + red[1] + red[2] + red[3];
        stats[bp * 2 + 0] = m;
        stats[bp * 2 + 1] = 1.0f / ss;
    }
}

// -------- K5: out[b,q,p,d] = req_mask[b,p] * sum_t a[b,q,p,t]*T[b,q,t,d] -------
__global__ __launch_bounds__(256) void out_kernel(
    const float* __restrict__ e, const float* __restrict__ stats,
    const float* __restrict__ exp_tokens, const int* __restrict__ req_mask,
    float* __restrict__ out) {
    __shared__ float w_s[LE_ * P_];  // [t][p]
    int bq = blockIdx.x >> 1, half = blockIdx.x & 1;
    int b = bq >> 5;  // Q=32
    int tid = threadIdx.x;

#pragma unroll
    for (int i = 0; i < 16; ++i) {
        int idx = tid + i * 256;  // 0..4095
        int p = idx >> 7, t = idx & 127;
        int bp = b * P_ + p;
        float m = stats[bp * 2 + 0];
        float rm = req_mask[bp] ? stats[bp * 2 + 1] : 0.0f;
        float ev = e[(size_t)(bq * P_ + p) * LE_ + t];
        w_s[t * P_ + p] = __expf(ev - m) * rm;
    }
    __syncthreads();

    int d = half * 256 + tid;
    const float* T = exp_tokens + (size_t)bq * LE_ * D_;
    float acc[32];
#pragma unroll
    for (int p = 0; p < 32; ++p) acc[p] = 0.0f;

#pragma unroll 4
    for (int t = 0; t < LE_; ++t) {
        float tv = T[(size_t)t * D_ + d];
        const float4* wp = (const float4*)&w_s[t * P_];
#pragma unroll
        for (int j = 0; j < 8; ++j) {
            float4 w = wp[j];
            acc[j * 4 + 0] = fmaf(w.x, tv, acc[j * 4 + 0]);
            acc[j * 4 + 1] = fmaf(w.y, tv, acc[j * 4 + 1]);
            acc[j * 4 + 2] = fmaf(w.z, tv, acc[j * 4 + 2]);
            acc[j * 4 + 3] = fmaf(w.w, tv, acc[j * 4 + 3]);
        }
    }
    float* obase = out + (size_t)(bq * P_) * D_ + d;
#pragma unroll
    for (int p = 0; p < 32; ++p)
        obase[(size_t)p * D_] = acc[p];
}

extern "C" void kernel_launch(void* const* d_in, const int* in_sizes, int n_in,
                              void* d_out, int out_size, void* d_ws, size_t ws_size,
                              hipStream_t stream) {
    const float* exp_tokens = (const float*)d_in[0];
    const int*   exp_mask   = (const int*)d_in[1];
    const float* s_j        = (const float*)d_in[2];
    const int*   req_mask   = (const int*)d_in[3];
    const float* Ws_w       = (const float*)d_in[4];
    const float* Ws_b       = (const float*)d_in[5];
    const float* U_w        = (const float*)d_in[6];
    const float* v_w        = (const float*)d_in[7];
    float* out = (float*)d_out;

    float* ws_buf = (float*)d_ws;                         // B*P*A      = 32768   (EW)
    float* uh     = ws_buf + B_ * P_ * A_;                // B*Q*LE*A   = 4194304 (EU)
    float* e      = uh + (size_t)B_ * Q_ * LE_ * A_;      // B*Q*P*LE   = 1048576
    float* stats  = e + (size_t)B_ * Q_ * P_ * LE_;       // 2*B*P      = 512

    ws_kernel<<<dim3(B_ * P_), dim3(128), 0, stream>>>(s_j, Ws_w, Ws_b, ws_buf);
    uh_mfma_kernel<<<dim3(B_ * Q_ * LE_ / TM_), dim3(256), 0, stream>>>(exp_tokens, U_w, uh);
    score_kernel<<<dim3(B_ * Q_ * 4), dim3(256), 0, stream>>>(uh, ws_buf, v_w, exp_mask, e);
    softmax_stats_kernel<<<dim3(B_ * P_), dim3(256), 0, stream>>>(e, stats);
    out_kernel<<<dim3(B_ * Q_ * 2), dim3(256), 0, stream>>>(e, stats, exp_tokens, req_mask, out);
}